// Round 19
// baseline (405.112 us; speedup 1.0000x reference)
//
#include <hip/hip_runtime.h>

typedef __attribute__((ext_vector_type(4))) float f32x4;
typedef __attribute__((ext_vector_type(8))) __bf16 bf16x8;
typedef __attribute__((ext_vector_type(8))) unsigned short us8;
typedef __attribute__((ext_vector_type(4))) unsigned short us4;
typedef unsigned short u16;

#define SSILU_SCALE (1.0f / 0.6f)
#define INV_SQRT2 0.70710678118654752f

__device__ __forceinline__ u16 f2bf(float f) {
    __bf16 h = (__bf16)f;
    return __builtin_bit_cast(u16, h);
}
__device__ __forceinline__ float bf2f(u16 h) {
    union { unsigned int u; float f; } v; v.u = ((unsigned int)h) << 16;
    return v.f;
}
// plain silu (SSILU_SCALE folded into resid weights / Wout)
__device__ __forceinline__ float silu_(float x) {
    float e = __expf(-x);
    float s = __builtin_amdgcn_rcpf(1.0f + e);
    return x * s;
}

// ---------------------------------------------------------------------------
// prep: (unchanged)
//  WinF : W_in as B-fragments [kt20][w4][kk2][n4][lane64][8]   (UNscaled)
//  Wfrag: 4 resid matrices as [g][w4][kk8][n4][lane64][8], PRE-SCALED by
//         SSILU_SCALE.
// ---------------------------------------------------------------------------
__global__ __launch_bounds__(256) void prep_kernel(
    const float* __restrict__ Win, const float* __restrict__ W1a,
    const float* __restrict__ W1b, const float* __restrict__ W2a,
    const float* __restrict__ W2b, u16* __restrict__ WinF,
    u16* __restrict__ Wfrag, float* __restrict__ out, int outN) {
    int i = blockIdx.x * 256 + threadIdx.x;
    if (i < 327680) {
        int e = i & 7, lane = (i >> 3) & 63, n = (i >> 9) & 3;
        int kk = (i >> 11) & 1, w = (i >> 12) & 3, kt = i >> 14;
        int lo = lane & 15, hi = lane >> 4;
        int k = kt * 64 + kk * 32 + hi * 8 + e;
        int col = w * 64 + n * 16 + lo;
        WinF[i] = f2bf(Win[k * 256 + col]);
        return;
    }
    int j = i - 327680;
    if (j < 262144) {
        int g = j >> 16, r = j & 65535;
        int chunk = r >> 9, within = r & 511;
        int lane = within >> 3, e = within & 7;
        int w = chunk >> 5, kk = (chunk >> 2) & 7, n = chunk & 3;
        int lo = lane & 15, hi = lane >> 4;
        int col = w * 64 + n * 16 + lo;
        int k = kk * 32 + hi * 8 + e;
        const float* W = (g == 0) ? W1a : (g == 1) ? W1b : (g == 2) ? W2a : W2b;
        Wfrag[j] = f2bf(W[k * 256 + col] * SSILU_SCALE);
        return;
    }
    int z = j - 262144;
    if (z < outN) out[z] = 0.0f;
}

// ---------------------------------------------------------------------------
// fused: 128 edge-rows per block, 8 waves (wave w: row-half hh=w>>2, cols
// 64*(w&3)..). 1 block/CU (130KB LDS), 8 waves/CU. Waves w and w+4 stream
// IDENTICAL B-fragments near-simultaneously -> L1 hits halve L2 traffic,
// attacking the measured phase-2 L2-BW bound. Per-wave code = champion
// (swapped-operand MFMA, packed us4 epilogues, BK=128 + 2-deep A prefetch,
// 3-set rotating B).
// ---------------------------------------------------------------------------
__global__ __launch_bounds__(512, 2) void fused_kernel(
    const float* __restrict__ A, const u16* __restrict__ WinF,
    const u16* __restrict__ Wfrag, const float* __restrict__ Wout,
    const float* __restrict__ evec, const int* __restrict__ eidx,
    float* __restrict__ out, int E) {
    __shared__ u16 xb[128 * 256];   // 64KB swizzled x tile (512B rows)
    __shared__ u16 tb[128 * 256];   // 64KB temp; = 2x32KB A dbuf in phase 1
    __shared__ float fpart[4][128];
    const int t = threadIdx.x, w = t >> 6, l = t & 63;
    const int hh = w >> 2, wq = w & 3;
    const int lo = l & 15, hi = l >> 4;
    const int swz = (lo & 7) << 4;
    const long rowbase = (long)blockIdx.x * 128;
    char* xbB = (char*)xb;
    char* tbB = (char*)tb;
    char* As0 = tbB;                // 32KB: 128 rows x 256B (128 k bf16)
    char* As1 = tbB + 32768;

    f32x4 acc[4][4];
#pragma unroll
    for (int m = 0; m < 4; m++)
#pragma unroll
        for (int n = 0; n < 4; n++) acc[m][n] = (f32x4){0.f, 0.f, 0.f, 0.f};

    // byte offset of acc[m][n]'s 4-elem run in the [row][col] swizzled tile
    auto RUNOFF = [&](int m, int n) {
        int row = hh * 64 + m * 16 + lo;
        int colb = (wq * 64 + n * 16 + hi * 4) * 2;
        return row * 512 + (colb ^ ((row & 7) << 4));
    };

    // ---------------- phase 1: y = x_cat @ W_in, BK=128 ----------------
    float4 va0[4][2], va1[4][2];
    auto LOADA = [&](int kb, float4 (&va)[4][2]) {
#pragma unroll
        for (int c = 0; c < 4; ++c) {
            int idx = t + c * 512;
            int r = idx >> 4, k8 = (idx & 15) * 8;
            long gr = rowbase + r;
            if (gr >= E) gr = E - 1;              // tail-block clamp
            const float* s = A + gr * 1280 + kb + k8;
            va[c][0] = *(const float4*)s;
            va[c][1] = *(const float4*)(s + 4);
        }
    };
    auto WRITEA = [&](char* dst, const float4 (&va)[4][2]) {
#pragma unroll
        for (int c = 0; c < 4; ++c) {
            int idx = t + c * 512;
            int r = idx >> 4, k8 = (idx & 15) * 8;
            us8 p;
            p[0] = f2bf(va[c][0].x); p[1] = f2bf(va[c][0].y);
            p[2] = f2bf(va[c][0].z); p[3] = f2bf(va[c][0].w);
            p[4] = f2bf(va[c][1].x); p[5] = f2bf(va[c][1].y);
            p[6] = f2bf(va[c][1].z); p[7] = f2bf(va[c][1].w);
            *(us8*)(dst + r * 256 + ((k8 * 2) ^ ((r & 7) << 4))) = p;
        }
    };
    const u16* WinFw = WinF + wq * 4096 + l * 8;
    auto LOADB = [&](int kt, bf16x8 (&b)[8]) {
        const u16* base = WinFw + kt * 16384;
#pragma unroll
        for (int kkL = 0; kkL < 2; ++kkL)
#pragma unroll
            for (int n = 0; n < 4; ++n)
                b[kkL * 4 + n] = __builtin_bit_cast(bf16x8,
                    *(const us8*)(base + kkL * 2048 + n * 512));
    };
    auto MFMA_HALF = [&](const char* AB, int kh, const bf16x8 (&b)[8]) {
#pragma unroll
        for (int kkL = 0; kkL < 2; ++kkL) {
            int kbyte = (kh * 2 + kkL) * 64 + hi * 16;
            bf16x8 af[4];
#pragma unroll
            for (int m = 0; m < 4; m++) {
                int r = hh * 64 + m * 16 + lo;
                af[m] = __builtin_bit_cast(bf16x8,
                    *(const us8*)(AB + r * 256 + (kbyte ^ swz)));
            }
#pragma unroll
            for (int m = 0; m < 4; m++)
#pragma unroll
                for (int n = 0; n < 4; n++)
                    acc[m][n] = __builtin_amdgcn_mfma_f32_16x16x32_bf16(
                        b[kkL * 4 + n], af[m], acc[m][n], 0, 0, 0);   // swapped
        }
    };
    auto FENCE = [&]() {
        asm volatile("s_waitcnt lgkmcnt(0)" ::: "memory");
        __builtin_amdgcn_sched_barrier(0);
        __builtin_amdgcn_s_barrier();
    };

    {
        bf16x8 bc[8], bn[8];

        // prologue: As0 <- A(0) (via va0); va1 <- A(1); bc <- B(tile 0)
        LOADA(0, va0);
        WRITEA(As0, va0);
        LOADB(0, bc);
        LOADA(128, va1);
        FENCE();

        auto STEP = [&](int s, const char* AScur, char* ASnxt,
                        const float4 (&vaCons)[4][2], float4 (&vaFill)[4][2]) {
            const bool more = (s < 9);
            if (s <= 7) LOADA((s + 2) * 128, vaFill);   // ~1.5 steps of cover
            LOADB(2 * s + 1, bn);
            __builtin_amdgcn_sched_barrier(0);
            MFMA_HALF(AScur, 0, bc);
            if (more) LOADB(2 * s + 2, bc);
            MFMA_HALF(AScur, 1, bn);
            if (more) WRITEA(ASnxt, vaCons);
            FENCE();
        };

        for (int i = 0; i < 5; ++i) {
            STEP(2 * i,     As0, As1, va1, va0);
            STEP(2 * i + 1, As1, As0, va0, va1);
        }
    }

    // epilogue: x1' = silu(y) -> xb, packed b64
#pragma unroll
    for (int m = 0; m < 4; m++)
#pragma unroll
        for (int n = 0; n < 4; n++) {
            us4 p;
#pragma unroll
            for (int j = 0; j < 4; j++) p[j] = f2bf(silu_(acc[m][n][j]));
            *(us4*)(xbB + RUNOFF(m, n)) = p;
        }

    // ---------------- phase 2: residual stack, 3-set rotating B ----------
    const u16* Wfw = Wfrag + wq * 16384;
    bf16x8 b0[4], b1[4], b2[4];

    auto LW = [&](const u16* Wg, int kk, bf16x8 (&b)[4]) {
        const u16* base = Wg + kk * 2048 + l * 8;
#pragma unroll
        for (int n = 0; n < 4; ++n)
            b[n] = __builtin_bit_cast(bf16x8, *(const us8*)(base + n * 512));
    };
    auto GEMM = [&](const char* AB, const u16* Wg) {
#pragma unroll
        for (int m = 0; m < 4; m++)
#pragma unroll
            for (int n = 0; n < 4; n++) acc[m][n] = (f32x4){0.f, 0.f, 0.f, 0.f};
#pragma unroll
        for (int kk = 0; kk < 8; ++kk) {
            if (kk < 6) {
                const int s = (kk + 2) % 3;
                if (s == 0)      LW(Wg, kk + 2, b0);
                else if (s == 1) LW(Wg, kk + 2, b1);
                else             LW(Wg, kk + 2, b2);
            }
            int kbyte = kk * 64 + hi * 16;
            bf16x8 af[4];
#pragma unroll
            for (int m = 0; m < 4; m++) {
                int r = hh * 64 + m * 16 + lo;
                af[m] = __builtin_bit_cast(bf16x8,
                    *(const us8*)(AB + r * 512 + (kbyte ^ ((r & 7) << 4))));
            }
            const bf16x8 (&bu)[4] = (kk % 3 == 0) ? b0 : (kk % 3 == 1) ? b1 : b2;
#pragma unroll
            for (int m = 0; m < 4; m++)
#pragma unroll
                for (int n = 0; n < 4; n++)
                    acc[m][n] = __builtin_amdgcn_mfma_f32_16x16x32_bf16(
                        bu[n], af[m], acc[m][n], 0, 0, 0);   // swapped
        }
    };

    // G1: t' = silu(x1' @ sW1a) -> tb
    LW(Wfw + 0 * 65536, 0, b0);
    LW(Wfw + 0 * 65536, 1, b1);
    FENCE();
    GEMM(xbB, Wfw + 0 * 65536);
#pragma unroll
    for (int m = 0; m < 4; m++)
#pragma unroll
        for (int n = 0; n < 4; n++) {
            us4 p;
#pragma unroll
            for (int j = 0; j < 4; j++) p[j] = f2bf(silu_(acc[m][n][j]));
            *(us4*)(tbB + RUNOFF(m, n)) = p;
        }
    LW(Wfw + 1 * 65536, 0, b0);
    LW(Wfw + 1 * 65536, 1, b1);
    FENCE();

    // G2: x2' = (x1' + silu(t' @ sW1b)) * INV_SQRT2 -> xb (packed rmw)
    GEMM(tbB, Wfw + 1 * 65536);
#pragma unroll
    for (int m = 0; m < 4; m++)
#pragma unroll
        for (int n = 0; n < 4; n++) {
            char* p = xbB + RUNOFF(m, n);
            us4 xv = *(const us4*)p;
            us4 o;
#pragma unroll
            for (int j = 0; j < 4; j++)
                o[j] = f2bf((bf2f(xv[j]) + silu_(acc[m][n][j])) * INV_SQRT2);
            *(us4*)p = o;
        }
    LW(Wfw + 2 * 65536, 0, b0);
    LW(Wfw + 2 * 65536, 1, b1);
    FENCE();

    // G3: t2' = silu(x2' @ sW2a) -> tb
    GEMM(xbB, Wfw + 2 * 65536);
#pragma unroll
    for (int m = 0; m < 4; m++)
#pragma unroll
        for (int n = 0; n < 4; n++) {
            us4 p;
#pragma unroll
            for (int j = 0; j < 4; j++) p[j] = f2bf(silu_(acc[m][n][j]));
            *(us4*)(tbB + RUNOFF(m, n)) = p;
        }
    LW(Wfw + 3 * 65536, 0, b0);
    LW(Wfw + 3 * 65536, 1, b1);
    FENCE();

    // G4: xf' = (x2' + silu(t2' @ sW2b)) * INV_SQRT2; dot (s*Wout)
    GEMM(tbB, Wfw + 3 * 65536);
    float wo2[4][4];
#pragma unroll
    for (int n = 0; n < 4; n++)
#pragma unroll
        for (int j = 0; j < 4; j++)
            wo2[n][j] = Wout[wq * 64 + n * 16 + hi * 4 + j] * SSILU_SCALE;

    float part[4];
#pragma unroll
    for (int m = 0; m < 4; m++) part[m] = 0.f;
#pragma unroll
    for (int m = 0; m < 4; m++)
#pragma unroll
        for (int n = 0; n < 4; n++) {
            const char* p = xbB + RUNOFF(m, n);
            us4 xv = *(const us4*)p;
#pragma unroll
            for (int j = 0; j < 4; j++) {
                float xf = (bf2f(xv[j]) + silu_(acc[m][n][j])) * INV_SQRT2;
                part[m] += xf * wo2[n][j];
            }
        }
    // reduce over hi (lanes l, l^16, l^32): combine the 4 hi-groups
#pragma unroll
    for (int m = 0; m < 4; m++) {
        float v = part[m];
        v += __shfl_xor(v, 16);
        v += __shfl_xor(v, 32);
        if (hi == 0) fpart[wq][hh * 64 + m * 16 + lo] = v;
    }
    __syncthreads();

    if (t < 128) {
        int r = t;
        long e = rowbase + r;
        if (e < E) {
            float F = fpart[0][r] + fpart[1][r] + fpart[2][r] + fpart[3][r];
            float vx = evec[e * 3 + 0], vy = evec[e * 3 + 1], vz = evec[e * 3 + 2];
            int a = eidx[e];
            atomicAdd(&out[a * 3 + 0], F * vx);
            atomicAdd(&out[a * 3 + 1], F * vy);
            atomicAdd(&out[a * 3 + 2], F * vz);
        }
    }
}

extern "C" void kernel_launch(void* const* d_in, const int* in_sizes, int n_in,
                              void* d_out, int out_size, void* d_ws, size_t ws_size,
                              hipStream_t stream) {
    const float* x_cat = (const float*)d_in[0];
    const float* evec  = (const float*)d_in[1];
    const int*   eidx  = (const int*)d_in[2];
    const float* Win   = (const float*)d_in[3];
    const float* W1a   = (const float*)d_in[4];
    const float* W1b   = (const float*)d_in[5];
    const float* W2a   = (const float*)d_in[6];
    const float* W2b   = (const float*)d_in[7];
    const float* Wout  = (const float*)d_in[8];
    float* out = (float*)d_out;
    const int E = in_sizes[1] / 3;   // 200000

    u16* WinF  = (u16*)d_ws;          // 327680 elems
    u16* Wfrag = WinF + 327680;       // 262144 elems

    int prepN = 327680 + 262144 + out_size;
    prep_kernel<<<(prepN + 255) / 256, 256, 0, stream>>>(
        Win, W1a, W1b, W2a, W2b, WinF, Wfrag, out, out_size);
    fused_kernel<<<(E + 127) / 128, 512, 0, stream>>>(
        x_cat, WinF, Wfrag, Wout, evec, eidx, out, E);
}

// Round 20
// 366.258 us; speedup vs baseline: 1.1061x; 1.1061x over previous
//
#include <hip/hip_runtime.h>

typedef __attribute__((ext_vector_type(4))) float f32x4;
typedef __attribute__((ext_vector_type(8))) __bf16 bf16x8;
typedef __attribute__((ext_vector_type(8))) unsigned short us8;
typedef __attribute__((ext_vector_type(4))) unsigned short us4;
typedef unsigned short u16;

#define SSILU_SCALE (1.0f / 0.6f)
#define INV_SQRT2 0.70710678118654752f

__device__ __forceinline__ u16 f2bf(float f) {
    __bf16 h = (__bf16)f;
    return __builtin_bit_cast(u16, h);
}
__device__ __forceinline__ float bf2f(u16 h) {
    union { unsigned int u; float f; } v; v.u = ((unsigned int)h) << 16;
    return v.f;
}
// plain silu (SSILU_SCALE folded into resid weights / Wout)
__device__ __forceinline__ float silu_(float x) {
    float e = __expf(-x);
    float s = __builtin_amdgcn_rcpf(1.0f + e);
    return x * s;
}

// ---------------------------------------------------------------------------
// prep:
//  WinF : W_in as B-fragments [kt20][w4][kk2][n4][lane64][8]   (UNscaled)
//  Wfrag: 4 resid matrices as [g][w4][kk8][n4][lane64][8], PRE-SCALED by
//         SSILU_SCALE.
// ---------------------------------------------------------------------------
__global__ __launch_bounds__(256) void prep_kernel(
    const float* __restrict__ Win, const float* __restrict__ W1a,
    const float* __restrict__ W1b, const float* __restrict__ W2a,
    const float* __restrict__ W2b, u16* __restrict__ WinF,
    u16* __restrict__ Wfrag, float* __restrict__ out, int outN) {
    int i = blockIdx.x * 256 + threadIdx.x;
    if (i < 327680) {
        int e = i & 7, lane = (i >> 3) & 63, n = (i >> 9) & 3;
        int kk = (i >> 11) & 1, w = (i >> 12) & 3, kt = i >> 14;
        int lo = lane & 15, hi = lane >> 4;
        int k = kt * 64 + kk * 32 + hi * 8 + e;
        int col = w * 64 + n * 16 + lo;
        WinF[i] = f2bf(Win[k * 256 + col]);
        return;
    }
    int j = i - 327680;
    if (j < 262144) {
        int g = j >> 16, r = j & 65535;
        int chunk = r >> 9, within = r & 511;
        int lane = within >> 3, e = within & 7;
        int w = chunk >> 5, kk = (chunk >> 2) & 7, n = chunk & 3;
        int lo = lane & 15, hi = lane >> 4;
        int col = w * 64 + n * 16 + lo;
        int k = kk * 32 + hi * 8 + e;
        const float* W = (g == 0) ? W1a : (g == 1) ? W1b : (g == 2) ? W2a : W2b;
        Wfrag[j] = f2bf(W[k * 256 + col] * SSILU_SCALE);
        return;
    }
    int z = j - 262144;
    if (z < outN) out[z] = 0.0f;
}

// ---------------------------------------------------------------------------
// fused (champion R18 + xr16 bf16 register residual + setprio in phase 2):
// 64 edge-rows, 4 waves. 65KB LDS, 2 blocks/CU. Swapped-operand MFMA,
// packed us4 epilogues, BK=128 + 2-deep A reg prefetch, 3-set rotating B.
// ---------------------------------------------------------------------------
__global__ __launch_bounds__(256, 2) void fused_kernel(
    const float* __restrict__ A, const u16* __restrict__ WinF,
    const u16* __restrict__ Wfrag, const float* __restrict__ Wout,
    const float* __restrict__ evec, const int* __restrict__ eidx,
    float* __restrict__ out) {
    __shared__ u16 xb[64 * 256];   // 32KB swizzled x tile (512B rows)
    __shared__ u16 tb[64 * 256];   // 32KB temp; = 2x16KB A dbuf in phase 1
    __shared__ float fpart[4][64];
    const int t = threadIdx.x, w = t >> 6, l = t & 63;
    const int lo = l & 15, hi = l >> 4;
    const int swz = (lo & 7) << 4;
    const long rowbase = (long)blockIdx.x * 64;
    char* xbB = (char*)xb;
    char* tbB = (char*)tb;
    char* As0 = tbB;                // 16KB: 64 rows x 256B (128 k bf16)
    char* As1 = tbB + 16384;

    f32x4 acc[4][4];
#pragma unroll
    for (int m = 0; m < 4; m++)
#pragma unroll
        for (int n = 0; n < 4; n++) acc[m][n] = (f32x4){0.f, 0.f, 0.f, 0.f};

    // byte offset of acc[m][n]'s 4-elem run in a [row][col] swizzled tile
    auto RUNOFF = [&](int m, int n) {
        int row = m * 16 + lo;
        int colb = (w * 64 + n * 16 + hi * 4) * 2;
        return row * 512 + (colb ^ ((row & 7) << 4));
    };

    // ---------------- phase 1: y = x_cat @ W_in, BK=128 ----------------
    float4 va0[4][2], va1[4][2];   // two A register sets (A(k) -> set k&1)
    auto LOADA = [&](int kb, float4 (&va)[4][2]) {
#pragma unroll
        for (int c = 0; c < 4; ++c) {
            int idx = t + c * 256;
            int r = idx >> 4, k8 = (idx & 15) * 8;
            const float* s = A + (rowbase + r) * 1280 + kb + k8;
            va[c][0] = *(const float4*)s;
            va[c][1] = *(const float4*)(s + 4);
        }
    };
    auto WRITEA = [&](char* dst, const float4 (&va)[4][2]) {
#pragma unroll
        for (int c = 0; c < 4; ++c) {
            int idx = t + c * 256;
            int r = idx >> 4, k8 = (idx & 15) * 8;
            us8 p;
            p[0] = f2bf(va[c][0].x); p[1] = f2bf(va[c][0].y);
            p[2] = f2bf(va[c][0].z); p[3] = f2bf(va[c][0].w);
            p[4] = f2bf(va[c][1].x); p[5] = f2bf(va[c][1].y);
            p[6] = f2bf(va[c][1].z); p[7] = f2bf(va[c][1].w);
            *(us8*)(dst + r * 256 + ((k8 * 2) ^ ((r & 7) << 4))) = p;
        }
    };
    const u16* WinFw = WinF + w * 4096 + l * 8;
    auto LOADB = [&](int kt, bf16x8 (&b)[8]) {
        const u16* base = WinFw + kt * 16384;
#pragma unroll
        for (int kkL = 0; kkL < 2; ++kkL)
#pragma unroll
            for (int n = 0; n < 4; ++n)
                b[kkL * 4 + n] = __builtin_bit_cast(bf16x8,
                    *(const us8*)(base + kkL * 2048 + n * 512));
    };
    auto MFMA_HALF = [&](const char* AB, int half, const bf16x8 (&b)[8]) {
#pragma unroll
        for (int kkL = 0; kkL < 2; ++kkL) {
            int kbyte = (half * 2 + kkL) * 64 + hi * 16;
            bf16x8 af[4];
#pragma unroll
            for (int m = 0; m < 4; m++) {
                int r = m * 16 + lo;
                af[m] = __builtin_bit_cast(bf16x8,
                    *(const us8*)(AB + r * 256 + (kbyte ^ swz)));
            }
#pragma unroll
            for (int m = 0; m < 4; m++)
#pragma unroll
                for (int n = 0; n < 4; n++)
                    acc[m][n] = __builtin_amdgcn_mfma_f32_16x16x32_bf16(
                        b[kkL * 4 + n], af[m], acc[m][n], 0, 0, 0);   // swapped
        }
    };
    auto FENCE = [&]() {
        asm volatile("s_waitcnt lgkmcnt(0)" ::: "memory");
        __builtin_amdgcn_sched_barrier(0);
        __builtin_amdgcn_s_barrier();
    };

    {
        bf16x8 bc[8], bn[8];

        // prologue: As0 <- A(0) (via va0); va1 <- A(1); bc <- B(tile 0)
        LOADA(0, va0);
        WRITEA(As0, va0);
        LOADB(0, bc);
        LOADA(128, va1);
        FENCE();

        auto STEP = [&](int s, const char* AScur, char* ASnxt,
                        const float4 (&vaCons)[4][2], float4 (&vaFill)[4][2]) {
            const bool more = (s < 9);
            if (s <= 7) LOADA((s + 2) * 128, vaFill);   // ~1.5 steps of cover
            LOADB(2 * s + 1, bn);
            __builtin_amdgcn_sched_barrier(0);
            MFMA_HALF(AScur, 0, bc);
            if (more) LOADB(2 * s + 2, bc);
            MFMA_HALF(AScur, 1, bn);
            if (more) WRITEA(ASnxt, vaCons);
            FENCE();
        };

        for (int i = 0; i < 5; ++i) {
            STEP(2 * i,     As0, As1, va1, va0);
            STEP(2 * i + 1, As1, As0, va0, va1);
        }
    }

    // epilogue: x1' = silu(y) -> xb (packed) + xr16 (bf16 regs, 32 VGPR)
    us4 xr16[4][4];
#pragma unroll
    for (int m = 0; m < 4; m++)
#pragma unroll
        for (int n = 0; n < 4; n++) {
            us4 p;
#pragma unroll
            for (int j = 0; j < 4; j++) p[j] = f2bf(silu_(acc[m][n][j]));
            xr16[m][n] = p;
            *(us4*)(xbB + RUNOFF(m, n)) = p;
        }

    // ---------------- phase 2: residual stack, 3-set rotating B ----------
    const u16* Wfw = Wfrag + w * 16384;
    bf16x8 b0[4], b1[4], b2[4];

    auto LW = [&](const u16* Wg, int kk, bf16x8 (&b)[4]) {
        const u16* base = Wg + kk * 2048 + l * 8;
#pragma unroll
        for (int n = 0; n < 4; ++n)
            b[n] = __builtin_bit_cast(bf16x8, *(const us8*)(base + n * 512));
    };
    auto GEMM = [&](const char* AB, const u16* Wg) {
#pragma unroll
        for (int m = 0; m < 4; m++)
#pragma unroll
            for (int n = 0; n < 4; n++) acc[m][n] = (f32x4){0.f, 0.f, 0.f, 0.f};
        __builtin_amdgcn_s_setprio(1);
#pragma unroll
        for (int kk = 0; kk < 8; ++kk) {
            if (kk < 6) {
                const int s = (kk + 2) % 3;
                if (s == 0)      LW(Wg, kk + 2, b0);
                else if (s == 1) LW(Wg, kk + 2, b1);
                else             LW(Wg, kk + 2, b2);
            }
            int kbyte = kk * 64 + hi * 16;
            bf16x8 af[4];
#pragma unroll
            for (int m = 0; m < 4; m++) {
                int r = m * 16 + lo;
                af[m] = __builtin_bit_cast(bf16x8,
                    *(const us8*)(AB + r * 512 + (kbyte ^ ((r & 7) << 4))));
            }
            const bf16x8 (&bu)[4] = (kk % 3 == 0) ? b0 : (kk % 3 == 1) ? b1 : b2;
#pragma unroll
            for (int m = 0; m < 4; m++)
#pragma unroll
                for (int n = 0; n < 4; n++)
                    acc[m][n] = __builtin_amdgcn_mfma_f32_16x16x32_bf16(
                        bu[n], af[m], acc[m][n], 0, 0, 0);   // swapped
        }
        __builtin_amdgcn_s_setprio(0);
    };

    // G1: t' = silu(x1' @ sW1a) -> tb
    LW(Wfw + 0 * 65536, 0, b0);
    LW(Wfw + 0 * 65536, 1, b1);
    FENCE();
    GEMM(xbB, Wfw + 0 * 65536);
#pragma unroll
    for (int m = 0; m < 4; m++)
#pragma unroll
        for (int n = 0; n < 4; n++) {
            us4 p;
#pragma unroll
            for (int j = 0; j < 4; j++) p[j] = f2bf(silu_(acc[m][n][j]));
            *(us4*)(tbB + RUNOFF(m, n)) = p;
        }
    LW(Wfw + 1 * 65536, 0, b0);
    LW(Wfw + 1 * 65536, 1, b1);
    FENCE();

    // G2: x2' = (x1' + silu(t' @ sW1b)) * INV_SQRT2 -> xr16 + xb
    GEMM(tbB, Wfw + 1 * 65536);
#pragma unroll
    for (int m = 0; m < 4; m++)
#pragma unroll
        for (int n = 0; n < 4; n++) {
            us4 xv = xr16[m][n];
            us4 o;
#pragma unroll
            for (int j = 0; j < 4; j++)
                o[j] = f2bf((bf2f(xv[j]) + silu_(acc[m][n][j])) * INV_SQRT2);
            xr16[m][n] = o;
            *(us4*)(xbB + RUNOFF(m, n)) = o;
        }
    LW(Wfw + 2 * 65536, 0, b0);
    LW(Wfw + 2 * 65536, 1, b1);
    FENCE();

    // G3: t2' = silu(x2' @ sW2a) -> tb
    GEMM(xbB, Wfw + 2 * 65536);
#pragma unroll
    for (int m = 0; m < 4; m++)
#pragma unroll
        for (int n = 0; n < 4; n++) {
            us4 p;
#pragma unroll
            for (int j = 0; j < 4; j++) p[j] = f2bf(silu_(acc[m][n][j]));
            *(us4*)(tbB + RUNOFF(m, n)) = p;
        }
    LW(Wfw + 3 * 65536, 0, b0);
    LW(Wfw + 3 * 65536, 1, b1);
    FENCE();

    // G4: xf' = (x2' + silu(t2' @ sW2b)) * INV_SQRT2; dot (s*Wout)
    GEMM(tbB, Wfw + 3 * 65536);
    float wo2[4][4];
#pragma unroll
    for (int n = 0; n < 4; n++)
#pragma unroll
        for (int j = 0; j < 4; j++)
            wo2[n][j] = Wout[w * 64 + n * 16 + hi * 4 + j] * SSILU_SCALE;

    float part[4];
#pragma unroll
    for (int m = 0; m < 4; m++) part[m] = 0.f;
#pragma unroll
    for (int m = 0; m < 4; m++)
#pragma unroll
        for (int n = 0; n < 4; n++) {
            us4 xv = xr16[m][n];
#pragma unroll
            for (int j = 0; j < 4; j++) {
                float xf = (bf2f(xv[j]) + silu_(acc[m][n][j])) * INV_SQRT2;
                part[m] += xf * wo2[n][j];
            }
        }
    // reduce over hi (lanes l, l^16, l^32): combine the 4 hi-groups
#pragma unroll
    for (int m = 0; m < 4; m++) {
        float v = part[m];
        v += __shfl_xor(v, 16);
        v += __shfl_xor(v, 32);
        if (hi == 0) fpart[w][m * 16 + lo] = v;
    }
    __syncthreads();

    if (t < 64) {
        int r = t;
        float F = fpart[0][r] + fpart[1][r] + fpart[2][r] + fpart[3][r];
        long e = rowbase + r;
        float vx = evec[e * 3 + 0], vy = evec[e * 3 + 1], vz = evec[e * 3 + 2];
        int a = eidx[e];
        atomicAdd(&out[a * 3 + 0], F * vx);
        atomicAdd(&out[a * 3 + 1], F * vy);
        atomicAdd(&out[a * 3 + 2], F * vz);
    }
}

extern "C" void kernel_launch(void* const* d_in, const int* in_sizes, int n_in,
                              void* d_out, int out_size, void* d_ws, size_t ws_size,
                              hipStream_t stream) {
    const float* x_cat = (const float*)d_in[0];
    const float* evec  = (const float*)d_in[1];
    const int*   eidx  = (const int*)d_in[2];
    const float* Win   = (const float*)d_in[3];
    const float* W1a   = (const float*)d_in[4];
    const float* W1b   = (const float*)d_in[5];
    const float* W2a   = (const float*)d_in[6];
    const float* W2b   = (const float*)d_in[7];
    const float* Wout  = (const float*)d_in[8];
    float* out = (float*)d_out;
    const int E = in_sizes[1] / 3;   // 200000

    u16* WinF  = (u16*)d_ws;          // 327680 elems
    u16* Wfrag = WinF + 327680;       // 262144 elems

    int prepN = 327680 + 262144 + out_size;
    prep_kernel<<<(prepN + 255) / 256, 256, 0, stream>>>(
        Win, W1a, W1b, W2a, W2b, WinF, Wfrag, out, out_size);
    fused_kernel<<<E / 64, 256, 0, stream>>>(
        x_cat, WinF, Wfrag, Wout, evec, eidx, out);
}

// Round 21
// 355.578 us; speedup vs baseline: 1.1393x; 1.0300x over previous
//
#include <hip/hip_runtime.h>

typedef __attribute__((ext_vector_type(4))) float f32x4;
typedef __attribute__((ext_vector_type(8))) __bf16 bf16x8;
typedef __attribute__((ext_vector_type(8))) unsigned short us8;
typedef __attribute__((ext_vector_type(4))) unsigned short us4;
typedef unsigned short u16;

#define SSILU_SCALE (1.0f / 0.6f)
#define INV_SQRT2 0.70710678118654752f

__device__ __forceinline__ u16 f2bf(float f) {
    __bf16 h = (__bf16)f;
    return __builtin_bit_cast(u16, h);
}
__device__ __forceinline__ float bf2f(u16 h) {
    union { unsigned int u; float f; } v; v.u = ((unsigned int)h) << 16;
    return v.f;
}
// plain silu (SSILU_SCALE folded into resid weights / Wout)
__device__ __forceinline__ float silu_(float x) {
    float e = __expf(-x);
    float s = __builtin_amdgcn_rcpf(1.0f + e);
    return x * s;
}

// ---------------------------------------------------------------------------
// prep:
//  WinF : W_in as B-fragments [kt20][w4][kk2][n4][lane64][8]   (UNscaled)
//  Wfrag: 4 resid matrices as [g][w4][kk8][n4][lane64][8], PRE-SCALED by
//         SSILU_SCALE (absorbs the ScaledSiLU scale of the PRECEDING layer).
// ---------------------------------------------------------------------------
__global__ __launch_bounds__(256) void prep_kernel(
    const float* __restrict__ Win, const float* __restrict__ W1a,
    const float* __restrict__ W1b, const float* __restrict__ W2a,
    const float* __restrict__ W2b, u16* __restrict__ WinF,
    u16* __restrict__ Wfrag, float* __restrict__ out, int outN) {
    int i = blockIdx.x * 256 + threadIdx.x;
    if (i < 327680) {
        int e = i & 7, lane = (i >> 3) & 63, n = (i >> 9) & 3;
        int kk = (i >> 11) & 1, w = (i >> 12) & 3, kt = i >> 14;
        int lo = lane & 15, hi = lane >> 4;
        int k = kt * 64 + kk * 32 + hi * 8 + e;
        int col = w * 64 + n * 16 + lo;
        WinF[i] = f2bf(Win[k * 256 + col]);
        return;
    }
    int j = i - 327680;
    if (j < 262144) {
        int g = j >> 16, r = j & 65535;
        int chunk = r >> 9, within = r & 511;
        int lane = within >> 3, e = within & 7;
        int w = chunk >> 5, kk = (chunk >> 2) & 7, n = chunk & 3;
        int lo = lane & 15, hi = lane >> 4;
        int col = w * 64 + n * 16 + lo;
        int k = kk * 32 + hi * 8 + e;
        const float* W = (g == 0) ? W1a : (g == 1) ? W1b : (g == 2) ? W2a : W2b;
        Wfrag[j] = f2bf(W[k * 256 + col] * SSILU_SCALE);
        return;
    }
    int z = j - 262144;
    if (z < outN) out[z] = 0.0f;
}

// ---------------------------------------------------------------------------
// fused: 64 edge-rows, 4 waves. 65KB LDS, 2 blocks/CU. Swapped-operand MFMA
// (acc = (x@W)^T fragments; packed us4 epilogues). Phase 1: BK=128 + 2-deep
// A reg prefetch. Phase 2: 3-set rotating B, packed xb readback (no xr regs;
// unscaled x' values, scale carried by pre-scaled weights).
// ---------------------------------------------------------------------------
__global__ __launch_bounds__(256, 2) void fused_kernel(
    const float* __restrict__ A, const u16* __restrict__ WinF,
    const u16* __restrict__ Wfrag, const float* __restrict__ Wout,
    const float* __restrict__ evec, const int* __restrict__ eidx,
    float* __restrict__ out) {
    __shared__ u16 xb[64 * 256];   // 32KB swizzled x tile (512B rows)
    __shared__ u16 tb[64 * 256];   // 32KB temp; = 2x16KB A dbuf in phase 1
    __shared__ float fpart[4][64];
    const int t = threadIdx.x, w = t >> 6, l = t & 63;
    const int lo = l & 15, hi = l >> 4;
    const int swz = (lo & 7) << 4;
    const long rowbase = (long)blockIdx.x * 64;
    char* xbB = (char*)xb;
    char* tbB = (char*)tb;
    char* As0 = tbB;                // 16KB: 64 rows x 256B (128 k bf16)
    char* As1 = tbB + 16384;

    f32x4 acc[4][4];
#pragma unroll
    for (int m = 0; m < 4; m++)
#pragma unroll
        for (int n = 0; n < 4; n++) acc[m][n] = (f32x4){0.f, 0.f, 0.f, 0.f};

    // byte offset of acc[m][n]'s 4-elem run in a [row][col] swizzled tile
    auto RUNOFF = [&](int m, int n) {
        int row = m * 16 + lo;
        int colb = (w * 64 + n * 16 + hi * 4) * 2;
        return row * 512 + (colb ^ ((row & 7) << 4));
    };

    // ---------------- phase 1: y = x_cat @ W_in, BK=128 ----------------
    float4 va0[4][2], va1[4][2];   // two A register sets (A(k) -> set k&1)
    auto LOADA = [&](int kb, float4 (&va)[4][2]) {
#pragma unroll
        for (int c = 0; c < 4; ++c) {
            int idx = t + c * 256;
            int r = idx >> 4, k8 = (idx & 15) * 8;
            const float* s = A + (rowbase + r) * 1280 + kb + k8;
            va[c][0] = *(const float4*)s;
            va[c][1] = *(const float4*)(s + 4);
        }
    };
    auto WRITEA = [&](char* dst, const float4 (&va)[4][2]) {
#pragma unroll
        for (int c = 0; c < 4; ++c) {
            int idx = t + c * 256;
            int r = idx >> 4, k8 = (idx & 15) * 8;
            us8 p;
            p[0] = f2bf(va[c][0].x); p[1] = f2bf(va[c][0].y);
            p[2] = f2bf(va[c][0].z); p[3] = f2bf(va[c][0].w);
            p[4] = f2bf(va[c][1].x); p[5] = f2bf(va[c][1].y);
            p[6] = f2bf(va[c][1].z); p[7] = f2bf(va[c][1].w);
            *(us8*)(dst + r * 256 + ((k8 * 2) ^ ((r & 7) << 4))) = p;
        }
    };
    const u16* WinFw = WinF + w * 4096 + l * 8;
    auto LOADB = [&](int kt, bf16x8 (&b)[8]) {
        const u16* base = WinFw + kt * 16384;
#pragma unroll
        for (int kkL = 0; kkL < 2; ++kkL)
#pragma unroll
            for (int n = 0; n < 4; ++n)
                b[kkL * 4 + n] = __builtin_bit_cast(bf16x8,
                    *(const us8*)(base + kkL * 2048 + n * 512));
    };
    auto MFMA_HALF = [&](const char* AB, int half, const bf16x8 (&b)[8]) {
#pragma unroll
        for (int kkL = 0; kkL < 2; ++kkL) {
            int kbyte = (half * 2 + kkL) * 64 + hi * 16;
            bf16x8 af[4];
#pragma unroll
            for (int m = 0; m < 4; m++) {
                int r = m * 16 + lo;
                af[m] = __builtin_bit_cast(bf16x8,
                    *(const us8*)(AB + r * 256 + (kbyte ^ swz)));
            }
#pragma unroll
            for (int m = 0; m < 4; m++)
#pragma unroll
                for (int n = 0; n < 4; n++)
                    acc[m][n] = __builtin_amdgcn_mfma_f32_16x16x32_bf16(
                        b[kkL * 4 + n], af[m], acc[m][n], 0, 0, 0);   // swapped
        }
    };
    auto FENCE = [&]() {
        asm volatile("s_waitcnt lgkmcnt(0)" ::: "memory");
        __builtin_amdgcn_sched_barrier(0);
        __builtin_amdgcn_s_barrier();
    };

    {
        bf16x8 bc[8], bn[8];

        // prologue: As0 <- A(0) (via va0); va1 <- A(1); bc <- B(tile 0)
        LOADA(0, va0);
        WRITEA(As0, va0);
        LOADB(0, bc);
        LOADA(128, va1);
        FENCE();

        auto STEP = [&](int s, const char* AScur, char* ASnxt,
                        const float4 (&vaCons)[4][2], float4 (&vaFill)[4][2]) {
            const bool more = (s < 9);
            if (s <= 7) LOADA((s + 2) * 128, vaFill);   // ~1.5 steps of cover
            LOADB(2 * s + 1, bn);
            __builtin_amdgcn_sched_barrier(0);
            MFMA_HALF(AScur, 0, bc);
            if (more) LOADB(2 * s + 2, bc);
            MFMA_HALF(AScur, 1, bn);
            if (more) WRITEA(ASnxt, vaCons);
            FENCE();
        };

        for (int i = 0; i < 5; ++i) {
            STEP(2 * i,     As0, As1, va1, va0);
            STEP(2 * i + 1, As1, As0, va0, va1);
        }
    }

    // epilogue: x1' = silu(y) -> xb, packed b64
#pragma unroll
    for (int m = 0; m < 4; m++)
#pragma unroll
        for (int n = 0; n < 4; n++) {
            us4 p;
#pragma unroll
            for (int j = 0; j < 4; j++) p[j] = f2bf(silu_(acc[m][n][j]));
            *(us4*)(xbB + RUNOFF(m, n)) = p;
        }

    // ---------------- phase 2: residual stack, 3-set rotating B ----------
    const u16* Wfw = Wfrag + w * 16384;
    bf16x8 b0[4], b1[4], b2[4];

    auto LW = [&](const u16* Wg, int kk, bf16x8 (&b)[4]) {
        const u16* base = Wg + kk * 2048 + l * 8;
#pragma unroll
        for (int n = 0; n < 4; ++n)
            b[n] = __builtin_bit_cast(bf16x8, *(const us8*)(base + n * 512));
    };
    auto GEMM = [&](const char* AB, const u16* Wg) {
#pragma unroll
        for (int m = 0; m < 4; m++)
#pragma unroll
            for (int n = 0; n < 4; n++) acc[m][n] = (f32x4){0.f, 0.f, 0.f, 0.f};
#pragma unroll
        for (int kk = 0; kk < 8; ++kk) {
            if (kk < 6) {
                const int s = (kk + 2) % 3;
                if (s == 0)      LW(Wg, kk + 2, b0);
                else if (s == 1) LW(Wg, kk + 2, b1);
                else             LW(Wg, kk + 2, b2);
            }
            int kbyte = kk * 64 + hi * 16;
            bf16x8 af[4];
#pragma unroll
            for (int m = 0; m < 4; m++) {
                int r = m * 16 + lo;
                af[m] = __builtin_bit_cast(bf16x8,
                    *(const us8*)(AB + r * 512 + (kbyte ^ ((r & 7) << 4))));
            }
            const bf16x8 (&bu)[4] = (kk % 3 == 0) ? b0 : (kk % 3 == 1) ? b1 : b2;
#pragma unroll
            for (int m = 0; m < 4; m++)
#pragma unroll
                for (int n = 0; n < 4; n++)
                    acc[m][n] = __builtin_amdgcn_mfma_f32_16x16x32_bf16(
                        bu[n], af[m], acc[m][n], 0, 0, 0);   // swapped
        }
    };

    // G1: t' = silu(x1' @ sW1a) -> tb
    LW(Wfw + 0 * 65536, 0, b0);
    LW(Wfw + 0 * 65536, 1, b1);
    FENCE();
    GEMM(xbB, Wfw + 0 * 65536);
#pragma unroll
    for (int m = 0; m < 4; m++)
#pragma unroll
        for (int n = 0; n < 4; n++) {
            us4 p;
#pragma unroll
            for (int j = 0; j < 4; j++) p[j] = f2bf(silu_(acc[m][n][j]));
            *(us4*)(tbB + RUNOFF(m, n)) = p;
        }
    LW(Wfw + 1 * 65536, 0, b0);
    LW(Wfw + 1 * 65536, 1, b1);
    FENCE();

    // G2: x2' = (x1' + silu(t' @ sW1b)) * INV_SQRT2 -> xb (packed rmw)
    GEMM(tbB, Wfw + 1 * 65536);
#pragma unroll
    for (int m = 0; m < 4; m++)
#pragma unroll
        for (int n = 0; n < 4; n++) {
            char* p = xbB + RUNOFF(m, n);
            us4 xv = *(const us4*)p;
            us4 o;
#pragma unroll
            for (int j = 0; j < 4; j++)
                o[j] = f2bf((bf2f(xv[j]) + silu_(acc[m][n][j])) * INV_SQRT2);
            *(us4*)p = o;
        }
    LW(Wfw + 2 * 65536, 0, b0);
    LW(Wfw + 2 * 65536, 1, b1);
    FENCE();

    // G3: t2' = silu(x2' @ sW2a) -> tb
    GEMM(xbB, Wfw + 2 * 65536);
#pragma unroll
    for (int m = 0; m < 4; m++)
#pragma unroll
        for (int n = 0; n < 4; n++) {
            us4 p;
#pragma unroll
            for (int j = 0; j < 4; j++) p[j] = f2bf(silu_(acc[m][n][j]));
            *(us4*)(tbB + RUNOFF(m, n)) = p;
        }
    LW(Wfw + 3 * 65536, 0, b0);
    LW(Wfw + 3 * 65536, 1, b1);
    FENCE();

    // G4: xf' = (x2' + silu(t2' @ sW2b)) * INV_SQRT2; dot (s*Wout)
    GEMM(tbB, Wfw + 3 * 65536);
    float wo2[4][4];
#pragma unroll
    for (int n = 0; n < 4; n++)
#pragma unroll
        for (int j = 0; j < 4; j++)
            wo2[n][j] = Wout[w * 64 + n * 16 + hi * 4 + j] * SSILU_SCALE;

    float part[4];
#pragma unroll
    for (int m = 0; m < 4; m++) part[m] = 0.f;
#pragma unroll
    for (int m = 0; m < 4; m++)
#pragma unroll
        for (int n = 0; n < 4; n++) {
            const char* p = xbB + RUNOFF(m, n);
            us4 xv = *(const us4*)p;
#pragma unroll
            for (int j = 0; j < 4; j++) {
                float xf = (bf2f(xv[j]) + silu_(acc[m][n][j])) * INV_SQRT2;
                part[m] += xf * wo2[n][j];
            }
        }
    // reduce over hi (lanes l, l^16, l^32): combine the 4 hi-groups
#pragma unroll
    for (int m = 0; m < 4; m++) {
        float v = part[m];
        v += __shfl_xor(v, 16);
        v += __shfl_xor(v, 32);
        if (hi == 0) fpart[w][m * 16 + lo] = v;
    }
    __syncthreads();

    if (t < 64) {
        int r = t;
        float F = fpart[0][r] + fpart[1][r] + fpart[2][r] + fpart[3][r];
        long e = rowbase + r;
        float vx = evec[e * 3 + 0], vy = evec[e * 3 + 1], vz = evec[e * 3 + 2];
        int a = eidx[e];
        atomicAdd(&out[a * 3 + 0], F * vx);
        atomicAdd(&out[a * 3 + 1], F * vy);
        atomicAdd(&out[a * 3 + 2], F * vz);
    }
}

extern "C" void kernel_launch(void* const* d_in, const int* in_sizes, int n_in,
                              void* d_out, int out_size, void* d_ws, size_t ws_size,
                              hipStream_t stream) {
    const float* x_cat = (const float*)d_in[0];
    const float* evec  = (const float*)d_in[1];
    const int*   eidx  = (const int*)d_in[2];
    const float* Win   = (const float*)d_in[3];
    const float* W1a   = (const float*)d_in[4];
    const float* W1b   = (const float*)d_in[5];
    const float* W2a   = (const float*)d_in[6];
    const float* W2b   = (const float*)d_in[7];
    const float* Wout  = (const float*)d_in[8];
    float* out = (float*)d_out;
    const int E = in_sizes[1] / 3;   // 200000

    u16* WinF  = (u16*)d_ws;          // 327680 elems
    u16* Wfrag = WinF + 327680;       // 262144 elems

    int prepN = 327680 + 262144 + out_size;
    prep_kernel<<<(prepN + 255) / 256, 256, 0, stream>>>(
        Win, W1a, W1b, W2a, W2b, WinF, Wfrag, out, out_size);
    fused_kernel<<<E / 64, 256, 0, stream>>>(
        x_cat, WinF, Wfrag, Wout, evec, eidx, out);
}